// Round 5
// baseline (459.551 us; speedup 1.0000x reference)
//
#include <hip/hip_runtime.h>

// Problem constants
#define NB 16
#define NS 8
#define NIMG (NB*NS)        // 128 images
#define CIN 3
#define HWDIM 128
#define FV 512
#define KOUT 10
#define STRIPS 8            // strip = 4 output rows (out 32x32, stride-4 7x7 SAME)
#define SROWS 4             // output rows per strip
#define WROWS 19            // input rows needed per channel: 4*3-1+6 - (-1) + 1
#define WIN_ROWS (CIN*WROWS)     // 57
#define WIN_STRIDE 136      // ushorts per row (272 B); slot = col + 1
#define NKT 6               // K-tiles of 32: 24 kb-blocks (21 real = ic*7+ky, 3 zero)
#define WTB_ELEMS (NKT*32*64*8)  // 98304 bf16 = 192 KB packed weight fragments

typedef __attribute__((ext_vector_type(8))) short bf16x8;   // 8 bf16 = 4 VGPR
typedef __attribute__((ext_vector_type(4))) float f32x4;    // MFMA acc

__device__ __forceinline__ unsigned short f2bf(float f) {   // RNE fp32->bf16
    unsigned int u = __float_as_uint(f);
    u = (u + 0x7FFFu + ((u >> 16) & 1u)) >> 16;
    return (unsigned short)u;
}

// ---------------------------------------------------------------------------
// Kernel 0: pack weights into MFMA B-fragment order.
// wtb[kt][ntile(32)][lane(64)][8]: lane l holds B[k=kt*32+(l>>4)*8+j][oc=nt*16+(l&15)]
// with k=(kb=ic*7+ky, kx=j); zero for kb>=21 or j==7.
// ---------------------------------------------------------------------------
__global__ void wprep_kernel(const float* __restrict__ cw,
                             unsigned short* __restrict__ wtb) {
    int i = blockIdx.x * 256 + threadIdx.x;        // < 98304
    int j  = i & 7;
    int l  = (i >> 3) & 63;
    int nt = (i >> 9) & 31;
    int kt = i >> 14;
    int oc = nt * 16 + (l & 15);
    int kb = kt * 4 + (l >> 4);
    unsigned short v = 0;
    if (kb < 21 && j < 7) {
        int ic = kb / 7, ky = kb - 7 * ic;
        v = f2bf(cw[(size_t)oc * 147 + ic * 49 + ky * 7 + j]);
    }
    wtb[i] = v;
}

// ---------------------------------------------------------------------------
// Kernel 1: bf16-MFMA implicit-GEMM conv + bias + ReLU + pool partials.
// WG = (image, 4-row strip); grid 1024 -> 4 blocks/CU (16 waves/CU).
// Staging: float4 global loads (7/thread), bf16 convert, 4x ds_write_b16.
// A-frag = 16B LDS read (two b64) at row(ic,ky,oy), col 4*ox-1 (slot=col+1,
// 8B aligned). Wave owns 2 x 64-oc columns; B-frags (24 x bf16x8) from
// global (L2-hot) reused over 2 M-supertiles.
// ---------------------------------------------------------------------------
__global__ __launch_bounds__(256, 4) void conv_mfma_kernel(
    const float* __restrict__ x, const unsigned short* __restrict__ wtb,
    const float* __restrict__ cb, float* __restrict__ partial)
{
    __shared__ unsigned short win[WIN_ROWS * WIN_STRIDE];   // 15,504 B

    int wg = blockIdx.x, img = wg >> 3, strip = wg & 7, tid = threadIdx.x;
    const float* ximg = x + (size_t)img * (CIN * HWDIM * HWDIM);
    int gr0 = strip * 16 - 1;            // SAME pad: 1 top/left

    // ---- zero pad slots: slot 0 and slots 129..135 of each row ----
    for (int i = tid; i < WIN_ROWS * 8; i += 256) {
        int row = i >> 3, z = i & 7;
        int slot = z ? 128 + z : 0;
        win[row * WIN_STRIDE + slot] = 0;
    }
    // ---- main staging: row = ic*19+rr, cols 4e..4e+3 -> slots 4e+1..4e+4 ----
    for (int i = tid; i < WIN_ROWS * 32; i += 256) {
        int row = i >> 5, e = i & 31;
        int ic = row / WROWS, rr = row - ic * WROWS;
        int gr = gr0 + rr;
        float4 v = {0.f, 0.f, 0.f, 0.f};
        if ((unsigned)gr < (unsigned)HWDIM)
            v = *(const float4*)(ximg + ((size_t)(ic * HWDIM + gr) << 7) + 4 * e);
        int base = row * WIN_STRIDE + 1 + 4 * e;
        win[base + 0] = f2bf(v.x);
        win[base + 1] = f2bf(v.y);
        win[base + 2] = f2bf(v.z);
        win[base + 3] = f2bf(v.w);
    }
    __syncthreads();

    int l = tid & 63, wv = tid >> 6;
    int m15 = l & 15, kgrp = l >> 4;

    // window row base per k-tile: kb = kt*4+kgrp -> (ic,ky); kb>=21 clamped
    // to (0,0) (B is zero there so the product contributes 0).
    int rowbase[NKT];
#pragma unroll
    for (int kt = 0; kt < NKT; ++kt) {
        int kb = kt * 4 + kgrp;
        int ic = (kb < 21) ? kb / 7 : 0;
        int ky = (kb < 21) ? kb - 7 * ic : 0;
        rowbase[kt] = ic * WROWS + ky;
    }

    for (int ncol = 0; ncol < 2; ++ncol) {
        int nbase = (wv * 2 + ncol) * 64;          // this wave's 64-oc column

        bf16x8 bf[NKT][4];
#pragma unroll
        for (int kt = 0; kt < NKT; ++kt)
#pragma unroll
            for (int nt = 0; nt < 4; ++nt) {
                int ntile = (nbase >> 4) + nt;
                bf[kt][nt] = *(const bf16x8*)(wtb +
                    (((size_t)(kt * 32 + ntile) * 64 + l) << 3));
            }
        float bias[4];
#pragma unroll
        for (int nt = 0; nt < 4; ++nt) bias[nt] = cb[nbase + nt * 16 + m15];
        float pool[4] = {0.f, 0.f, 0.f, 0.f};

        for (int mst = 0; mst < 2; ++mst) {        // 2 M-supertiles (2 rows each)
            f32x4 acc[4][4];
            const f32x4 z = {0.f, 0.f, 0.f, 0.f};
#pragma unroll
            for (int mt = 0; mt < 4; ++mt)
#pragma unroll
                for (int nt = 0; nt < 4; ++nt) acc[mt][nt] = z;

#pragma unroll
            for (int kt = 0; kt < NKT; ++kt) {
                bf16x8 at[4];
#pragma unroll
                for (int mt = 0; mt < 4; ++mt) {   // oy = mst*2+(mt>>1), parity mt&1
                    int row = rowbase[kt] + (mst * 2 + (mt >> 1)) * 4;
                    const unsigned short* p = win + row * WIN_STRIDE + 8 * m15 + 4 * (mt & 1);
                    union { unsigned long long q[2]; bf16x8 v; } u;
                    u.q[0] = *(const unsigned long long*)(p);
                    u.q[1] = *(const unsigned long long*)(p + 4);
                    at[mt] = u.v;
                }
#pragma unroll
                for (int mt = 0; mt < 4; ++mt)
#pragma unroll
                    for (int nt = 0; nt < 4; ++nt)
                        acc[mt][nt] = __builtin_amdgcn_mfma_f32_16x16x32_bf16(
                            at[mt], bf[kt][nt], acc[mt][nt], 0, 0, 0);
            }
            // bias + ReLU per conv output, accumulate pool partial per oc
#pragma unroll
            for (int mt = 0; mt < 4; ++mt)
#pragma unroll
                for (int nt = 0; nt < 4; ++nt)
#pragma unroll
                    for (int r = 0; r < 4; ++r)
                        pool[nt] += fmaxf(acc[mt][nt][r] + bias[nt], 0.f);
        }
        // reduce over the 4 k-chunk lane groups (disjoint positions)
#pragma unroll
        for (int nt = 0; nt < 4; ++nt) {
            float v = pool[nt];
            v += __shfl_xor(v, 16);
            v += __shfl_xor(v, 32);
            if (l < 16) partial[(size_t)wg * FV + nbase + nt * 16 + m15] = v;
        }
    }
}

// ---------------------------------------------------------------------------
// Kernel 2: per-sample head. float4 strip sums; per-wave projection (no
// per-k barriers).
// ---------------------------------------------------------------------------
__global__ __launch_bounds__(256) void head_kernel(
    const float* __restrict__ partial, const int* __restrict__ nslice,
    const float* __restrict__ q0, const float* __restrict__ pw,
    const float* __restrict__ pb, float* __restrict__ out)
{
    __shared__ float fvs[NS][FV];
    __shared__ float sc[NS];
    __shared__ float r0[FV];
    int b = blockIdx.x;
    int tid = threadIdx.x;

    // fvs: sum 8 strip partials, float4 vectorized
    for (int i = tid; i < NS * (FV / 4); i += 256) {
        int s = i >> 7, d4 = i & 127;
        const float* pp = partial + ((size_t)(b * NS + s) * STRIPS) * FV + 4 * d4;
        float4 a = {0.f, 0.f, 0.f, 0.f};
#pragma unroll
        for (int st = 0; st < STRIPS; ++st) {
            float4 v = *(const float4*)(pp + (size_t)st * FV);
            a.x += v.x; a.y += v.y; a.z += v.z; a.w += v.w;
        }
        const float sc4 = 1.f / 1024.f;
        float4 r = {a.x * sc4, a.y * sc4, a.z * sc4, a.w * sc4};
        *(float4*)&fvs[s][4 * d4] = r;
    }
    __syncthreads();

    // scores: 8 groups of 32 lanes, group = slice
    int grp = tid >> 5, l32 = tid & 31;
    float sdot = 0.f;
    for (int d = l32; d < FV; d += 32) sdot += q0[d] * fvs[grp][d];
    sdot += __shfl_down(sdot, 16, 32);
    sdot += __shfl_down(sdot, 8, 32);
    sdot += __shfl_down(sdot, 4, 32);
    sdot += __shfl_down(sdot, 2, 32);
    sdot += __shfl_down(sdot, 1, 32);
    if (l32 == 0) sc[grp] = sdot;
    __syncthreads();

    // masked softmax (uniform, computed redundantly per thread)
    int ns = nslice[b];
    float m = -3.0e38f;
    for (int s = 0; s < NS; ++s) if (s < ns) m = fmaxf(m, sc[s]);
    float ak[NS]; float se = 0.f;
    for (int s = 0; s < NS; ++s) {
        float e = (s < ns) ? expf(sc[s] - m) : 0.f;
        ak[s] = e; se += e;
    }
    float inv = 1.f / se;

    for (int d = tid; d < FV; d += 256) {
        float v = 0.f;
        for (int s = 0; s < NS; ++s) v += ak[s] * fvs[s][d];
        r0[d] = v * inv;
    }
    __syncthreads();

    // projection: wave wv handles k = wv, wv+4, wv+8 (no barriers)
    int wv = tid >> 6, l = tid & 63;
    for (int k = wv; k < KOUT; k += 4) {
        float p = 0.f;
#pragma unroll
        for (int t = 0; t < 8; ++t) p += r0[l + 64 * t] * pw[k * FV + l + 64 * t];
        p += __shfl_down(p, 32);
        p += __shfl_down(p, 16);
        p += __shfl_down(p, 8);
        p += __shfl_down(p, 4);
        p += __shfl_down(p, 2);
        p += __shfl_down(p, 1);
        if (l == 0) out[b * KOUT + k] = 1.f / (1.f + expf(-(p + pb[k])));
    }
}

extern "C" void kernel_launch(void* const* d_in, const int* in_sizes, int n_in,
                              void* d_out, int out_size, void* d_ws, size_t ws_size,
                              hipStream_t stream) {
    (void)in_sizes; (void)n_in; (void)out_size; (void)ws_size;
    const float* x      = (const float*)d_in[0];
    const int*   nslice = (const int*)d_in[1];
    const float* cw     = (const float*)d_in[2];
    const float* cb     = (const float*)d_in[3];
    const float* q0     = (const float*)d_in[4];
    const float* pw     = (const float*)d_in[5];
    const float* pb     = (const float*)d_in[6];
    float* out = (float*)d_out;

    float* partial = (float*)d_ws;          // 1024*512 f32 = 2 MB
    unsigned short* wtb = (unsigned short*)(partial + (size_t)NIMG * STRIPS * FV);

    wprep_kernel<<<WTB_ELEMS / 256, 256, 0, stream>>>(cw, wtb);
    conv_mfma_kernel<<<NIMG * STRIPS, 256, 0, stream>>>(x, wtb, cb, partial);
    head_kernel<<<NB, 256, 0, stream>>>(partial, nslice, q0, pw, pb, out);
}

// Round 8
// 150.984 us; speedup vs baseline: 3.0437x; 3.0437x over previous
//
#include <hip/hip_runtime.h>

// Problem constants
#define NB 16
#define NS 8
#define NIMG (NB*NS)        // 128 images
#define CIN 3
#define HWDIM 128
#define FV 512
#define KOUT 10
#define STRIPS 8            // strip = 4 output rows (out 32x32, stride-4 7x7 SAME)
#define WROWS 19            // input rows needed per channel for 4 output rows
#define WIN_ROWS (CIN*WROWS)     // 57
#define WIN_STRIDE 136      // ushorts per row (272 B); slot = col + 1
#define NKT 6               // K-tiles of 32: 24 kb-blocks (21 real = ic*7+ky, 3 zero)
#define WTB_ELEMS (NKT*32*64*8)  // 98304 bf16 = 192 KB packed weight fragments

typedef __attribute__((ext_vector_type(8))) short bf16x8;   // 8 bf16 = 4 VGPR
typedef __attribute__((ext_vector_type(4))) float f32x4;    // MFMA acc

__device__ __forceinline__ unsigned short f2bf(float f) {   // RNE fp32->bf16
    unsigned int u = __float_as_uint(f);
    u = (u + 0x7FFFu + ((u >> 16) & 1u)) >> 16;
    return (unsigned short)u;
}

// ---------------------------------------------------------------------------
// Kernel 0: pack weights into MFMA B-fragment order.
// wtb[kt][ntile(32)][lane(64)][8]: lane l holds B[k=kt*32+(l>>4)*8+j][oc=nt*16+(l&15)]
// with k=(kb=ic*7+ky, kx=j); zero for kb>=21 or j==7.
// ---------------------------------------------------------------------------
__global__ void wprep_kernel(const float* __restrict__ cw,
                             unsigned short* __restrict__ wtb) {
    int i = blockIdx.x * 256 + threadIdx.x;        // < 98304
    int j  = i & 7;
    int l  = (i >> 3) & 63;
    int nt = (i >> 9) & 31;
    int kt = i >> 14;
    int oc = nt * 16 + (l & 15);
    int kb = kt * 4 + (l >> 4);
    unsigned short v = 0;
    if (kb < 21 && j < 7) {
        int ic = kb / 7, ky = kb - 7 * ic;
        v = f2bf(cw[(size_t)oc * 147 + ic * 49 + ky * 7 + j]);
    }
    wtb[i] = v;
}

// ---------------------------------------------------------------------------
// Kernel 1: bf16-MFMA implicit-GEMM conv + bias + ReLU + pool partials.
// WG = (image, 4-row strip); grid 1024. Register plan: acc 64 + bfc 16 +
// at 16 + misc ~20 <= 128 -> true 4 waves/SIMD under launch_bounds(256,4).
// B-fragments loaded per k-tile from L2-hot wtb inside a NON-unrolled kt
// loop (prevents load hoisting / register blowup; TLP hides L2 latency).
// A-frag = 16B LDS read (two b64) at row(ic,ky,oy), col 4*ox-1.
// ---------------------------------------------------------------------------
__global__ __launch_bounds__(256, 4) void conv_mfma_kernel(
    const float* __restrict__ x, const unsigned short* __restrict__ wtb,
    const float* __restrict__ cb, float* __restrict__ partial)
{
    __shared__ unsigned short win[WIN_ROWS * WIN_STRIDE];   // 15,504 B

    int wg = blockIdx.x, img = wg >> 3, strip = wg & 7, tid = threadIdx.x;
    const float* ximg = x + (size_t)img * (CIN * HWDIM * HWDIM);
    int gr0 = strip * 16 - 1;            // SAME pad: 1 top/left

    // ---- zero pad slots: slot 0 and slots 129..135 of each row ----
    for (int i = tid; i < WIN_ROWS * 8; i += 256) {
        int row = i >> 3, z = i & 7;
        int slot = z ? 128 + z : 0;
        win[row * WIN_STRIDE + slot] = 0;
    }
    // ---- main staging: row = ic*19+rr, cols 4e..4e+3 -> slots 4e+1..4e+4 ----
    for (int i = tid; i < WIN_ROWS * 32; i += 256) {
        int row = i >> 5, e = i & 31;
        int ic = row / WROWS, rr = row - ic * WROWS;
        int gr = gr0 + rr;
        float4 v = {0.f, 0.f, 0.f, 0.f};
        if ((unsigned)gr < (unsigned)HWDIM)
            v = *(const float4*)(ximg + ((size_t)(ic * HWDIM + gr) << 7) + 4 * e);
        int base = row * WIN_STRIDE + 1 + 4 * e;
        win[base + 0] = f2bf(v.x);
        win[base + 1] = f2bf(v.y);
        win[base + 2] = f2bf(v.z);
        win[base + 3] = f2bf(v.w);
    }
    __syncthreads();

    int l = tid & 63, wv = tid >> 6;
    int m15 = l & 15, kgrp = l >> 4;

    for (int ncol = 0; ncol < 2; ++ncol) {
        int nbase = (wv * 2 + ncol) * 64;          // this wave's 64-oc column
        float bias[4];
#pragma unroll
        for (int nt = 0; nt < 4; ++nt) bias[nt] = cb[nbase + nt * 16 + m15];
        float pool[4] = {0.f, 0.f, 0.f, 0.f};

        for (int mst = 0; mst < 2; ++mst) {        // 2 M-supertiles (2 rows each)
            f32x4 acc[4][4];
            const f32x4 z = {0.f, 0.f, 0.f, 0.f};
#pragma unroll
            for (int mt = 0; mt < 4; ++mt)
#pragma unroll
                for (int nt = 0; nt < 4; ++nt) acc[mt][nt] = z;

#pragma unroll 1
            for (int kt = 0; kt < NKT; ++kt) {
                // B-fragments for this k-tile (L2-hot, coalesced 1KB/wave each)
                bf16x8 bfc[4];
#pragma unroll
                for (int nt = 0; nt < 4; ++nt)
                    bfc[nt] = *(const bf16x8*)(wtb +
                        (((size_t)(kt * 32 + (nbase >> 4) + nt) * 64 + l) << 3));

                // window row for this k-chunk: kb=(ic,ky); kb>=21 -> B is zero
                int kb = kt * 4 + kgrp;
                int ic = (kb < 21) ? kb / 7 : 0;
                int ky = (kb < 21) ? kb - 7 * ic : 0;
                int row0 = ic * WROWS + ky + mst * 8;

                bf16x8 at[4];
#pragma unroll
                for (int mt = 0; mt < 4; ++mt) {   // oy = mst*2+(mt>>1), parity mt&1
                    int row = row0 + (mt >> 1) * 4;
                    const unsigned short* p = win + row * WIN_STRIDE + 8 * m15 + 4 * (mt & 1);
                    union { unsigned long long q[2]; bf16x8 v; } u;
                    u.q[0] = *(const unsigned long long*)(p);
                    u.q[1] = *(const unsigned long long*)(p + 4);
                    at[mt] = u.v;
                }
#pragma unroll
                for (int mt = 0; mt < 4; ++mt)
#pragma unroll
                    for (int nt = 0; nt < 4; ++nt)
                        acc[mt][nt] = __builtin_amdgcn_mfma_f32_16x16x32_bf16(
                            at[mt], bfc[nt], acc[mt][nt], 0, 0, 0);
            }
            // bias + ReLU per conv output, accumulate pool partial per oc
#pragma unroll
            for (int mt = 0; mt < 4; ++mt)
#pragma unroll
                for (int nt = 0; nt < 4; ++nt)
#pragma unroll
                    for (int r = 0; r < 4; ++r)
                        pool[nt] += fmaxf(acc[mt][nt][r] + bias[nt], 0.f);
        }
        // reduce over the 4 k-chunk lane groups (disjoint positions)
#pragma unroll
        for (int nt = 0; nt < 4; ++nt) {
            float v = pool[nt];
            v += __shfl_xor(v, 16);
            v += __shfl_xor(v, 32);
            if (l < 16) partial[(size_t)wg * FV + nbase + nt * 16 + m15] = v;
        }
    }
}

// ---------------------------------------------------------------------------
// Kernel 2: per-sample head. float4 strip sums; per-wave projection.
// ---------------------------------------------------------------------------
__global__ __launch_bounds__(256) void head_kernel(
    const float* __restrict__ partial, const int* __restrict__ nslice,
    const float* __restrict__ q0, const float* __restrict__ pw,
    const float* __restrict__ pb, float* __restrict__ out)
{
    __shared__ float fvs[NS][FV];
    __shared__ float sc[NS];
    __shared__ float r0[FV];
    int b = blockIdx.x;
    int tid = threadIdx.x;

    for (int i = tid; i < NS * (FV / 4); i += 256) {
        int s = i >> 7, d4 = i & 127;
        const float* pp = partial + ((size_t)(b * NS + s) * STRIPS) * FV + 4 * d4;
        float4 a = {0.f, 0.f, 0.f, 0.f};
#pragma unroll
        for (int st = 0; st < STRIPS; ++st) {
            float4 v = *(const float4*)(pp + (size_t)st * FV);
            a.x += v.x; a.y += v.y; a.z += v.z; a.w += v.w;
        }
        const float sc4 = 1.f / 1024.f;
        float4 r = {a.x * sc4, a.y * sc4, a.z * sc4, a.w * sc4};
        *(float4*)&fvs[s][4 * d4] = r;
    }
    __syncthreads();

    int grp = tid >> 5, l32 = tid & 31;
    float sdot = 0.f;
    for (int d = l32; d < FV; d += 32) sdot += q0[d] * fvs[grp][d];
    sdot += __shfl_down(sdot, 16, 32);
    sdot += __shfl_down(sdot, 8, 32);
    sdot += __shfl_down(sdot, 4, 32);
    sdot += __shfl_down(sdot, 2, 32);
    sdot += __shfl_down(sdot, 1, 32);
    if (l32 == 0) sc[grp] = sdot;
    __syncthreads();

    int ns = nslice[b];
    float m = -3.0e38f;
    for (int s = 0; s < NS; ++s) if (s < ns) m = fmaxf(m, sc[s]);
    float ak[NS]; float se = 0.f;
    for (int s = 0; s < NS; ++s) {
        float e = (s < ns) ? expf(sc[s] - m) : 0.f;
        ak[s] = e; se += e;
    }
    float inv = 1.f / se;

    for (int d = tid; d < FV; d += 256) {
        float v = 0.f;
        for (int s = 0; s < NS; ++s) v += ak[s] * fvs[s][d];
        r0[d] = v * inv;
    }
    __syncthreads();

    int wv = tid >> 6, l = tid & 63;
    for (int k = wv; k < KOUT; k += 4) {
        float p = 0.f;
#pragma unroll
        for (int t = 0; t < 8; ++t) p += r0[l + 64 * t] * pw[k * FV + l + 64 * t];
        p += __shfl_down(p, 32);
        p += __shfl_down(p, 16);
        p += __shfl_down(p, 8);
        p += __shfl_down(p, 4);
        p += __shfl_down(p, 2);
        p += __shfl_down(p, 1);
        if (l == 0) out[b * KOUT + k] = 1.f / (1.f + expf(-(p + pb[k])));
    }
}

extern "C" void kernel_launch(void* const* d_in, const int* in_sizes, int n_in,
                              void* d_out, int out_size, void* d_ws, size_t ws_size,
                              hipStream_t stream) {
    (void)in_sizes; (void)n_in; (void)out_size; (void)ws_size;
    const float* x      = (const float*)d_in[0];
    const int*   nslice = (const int*)d_in[1];
    const float* cw     = (const float*)d_in[2];
    const float* cb     = (const float*)d_in[3];
    const float* q0     = (const float*)d_in[4];
    const float* pw     = (const float*)d_in[5];
    const float* pb     = (const float*)d_in[6];
    float* out = (float*)d_out;

    float* partial = (float*)d_ws;          // 1024*512 f32 = 2 MB
    unsigned short* wtb = (unsigned short*)(partial + (size_t)NIMG * STRIPS * FV);

    wprep_kernel<<<WTB_ELEMS / 256, 256, 0, stream>>>(cw, wtb);
    conv_mfma_kernel<<<NIMG * STRIPS, 256, 0, stream>>>(x, wtb, cb, partial);
    head_kernel<<<NB, 256, 0, stream>>>(partial, nslice, q0, pw, pb, out);
}

// Round 9
// 137.703 us; speedup vs baseline: 3.3373x; 1.0965x over previous
//
#include <hip/hip_runtime.h>

// Problem constants
#define NB 16
#define NS 8
#define NIMG (NB*NS)        // 128 images
#define CIN 3
#define HWDIM 128
#define FV 512
#define KOUT 10
#define STRIPS 8            // strip = 4 output rows (out 32x32, stride-4 7x7 SAME)
#define WROWS 19            // input rows needed per channel for 4 output rows
#define WIN_ROWS (CIN*WROWS)     // 57
#define WIN_STRIDE 136      // ushorts per row (272 B); slot = col + 1
#define NKT 6               // K-tiles of 32: 24 kb-blocks (21 real = ic*7+ky, 3 zero)
#define WTB_ELEMS (NKT*32*64*8)  // 98304 bf16 = 192 KB packed weight fragments

typedef __attribute__((ext_vector_type(8))) short bf16x8;   // 8 bf16 = 4 VGPR
typedef __attribute__((ext_vector_type(4))) float f32x4;    // MFMA acc

__device__ __forceinline__ unsigned short f2bf(float f) {   // RNE fp32->bf16
    unsigned int u = __float_as_uint(f);
    u = (u + 0x7FFFu + ((u >> 16) & 1u)) >> 16;
    return (unsigned short)u;
}

// ---------------------------------------------------------------------------
// Kernel 0: pack weights into MFMA B-fragment order.
// wtb[kt][ntile(32)][lane(64)][8]: lane l holds B[k=kt*32+(l>>4)*8+j][oc=nt*16+(l&15)]
// with k=(kb=ic*7+ky, kx=j); zero for kb>=21 or j==7.
// ---------------------------------------------------------------------------
__global__ void wprep_kernel(const float* __restrict__ cw,
                             unsigned short* __restrict__ wtb) {
    int i = blockIdx.x * 256 + threadIdx.x;        // < 98304
    int j  = i & 7;
    int l  = (i >> 3) & 63;
    int nt = (i >> 9) & 31;
    int kt = i >> 14;
    int oc = nt * 16 + (l & 15);
    int kb = kt * 4 + (l >> 4);
    unsigned short v = 0;
    if (kb < 21 && j < 7) {
        int ic = kb / 7, ky = kb - 7 * ic;
        v = f2bf(cw[(size_t)oc * 147 + ic * 49 + ky * 7 + j]);
    }
    wtb[i] = v;
}

__device__ __forceinline__ void load_bf(const unsigned short* __restrict__ wtb,
                                        int kt, int ntbase, int l, bf16x8 bfc[4]) {
#pragma unroll
    for (int nt = 0; nt < 4; ++nt)
        bfc[nt] = *(const bf16x8*)(wtb +
            (((size_t)(kt * 32 + ntbase + nt) * 64 + l) << 3));
}

__device__ __forceinline__ void compute_kt(
    const unsigned short* __restrict__ win, int kt, int kgrp, int m15, int mst,
    const bf16x8 bfc[4], f32x4 acc[4][4])
{
    // window row for this k-chunk: kb=(ic,ky); kb>=21 -> B is zero anyway
    int kb = kt * 4 + kgrp;
    int ic = (kb < 21) ? kb / 7 : 0;
    int ky = (kb < 21) ? kb - 7 * ic : 0;
    int row0 = ic * WROWS + ky + mst * 8;

    bf16x8 at[4];
#pragma unroll
    for (int mt = 0; mt < 4; ++mt) {               // oy = mst*2+(mt>>1), parity mt&1
        int row = row0 + (mt >> 1) * 4;
        const unsigned short* p = win + row * WIN_STRIDE + 8 * m15 + 4 * (mt & 1);
        union { unsigned long long q[2]; bf16x8 v; } u;
        u.q[0] = *(const unsigned long long*)(p);  // 8B-aligned
        u.q[1] = *(const unsigned long long*)(p + 4);
        at[mt] = u.v;
    }
#pragma unroll
    for (int mt = 0; mt < 4; ++mt)
#pragma unroll
        for (int nt = 0; nt < 4; ++nt)
            acc[mt][nt] = __builtin_amdgcn_mfma_f32_16x16x32_bf16(
                at[mt], bfc[nt], acc[mt][nt], 0, 0, 0);
}

// ---------------------------------------------------------------------------
// Kernel 1: bf16-MFMA implicit-GEMM conv + bias + ReLU + pool partials.
// WG = (image, 4-row strip); grid 1024; launch_bounds(256,3) -> unified
// budget ~170/wave. Register plan: acc 64 (AGPR) + B dbuf 32 + at 16 +
// misc ~30 = ~142 -> no spill, 3 blocks/CU (12 waves). B-fragments
// double-buffered: load(kt+1) issues before compute(kt) -> L2 latency
// hides under MFMAs + TLP. A-frag = 16B LDS read (two b64).
// ---------------------------------------------------------------------------
__global__ __launch_bounds__(256, 3) void conv_mfma_kernel(
    const float* __restrict__ x, const unsigned short* __restrict__ wtb,
    const float* __restrict__ cb, float* __restrict__ partial)
{
    __shared__ unsigned short win[WIN_ROWS * WIN_STRIDE];   // 15,504 B

    int wg = blockIdx.x, img = wg >> 3, strip = wg & 7, tid = threadIdx.x;
    const float* ximg = x + (size_t)img * (CIN * HWDIM * HWDIM);
    int gr0 = strip * 16 - 1;            // SAME pad: 1 top/left

    // ---- zero pad slots: slot 0 and slots 129..135 of each row ----
    for (int i = tid; i < WIN_ROWS * 8; i += 256) {
        int row = i >> 3, z = i & 7;
        int slot = z ? 128 + z : 0;
        win[row * WIN_STRIDE + slot] = 0;
    }
    // ---- main staging: row = ic*19+rr, cols 4e..4e+3 -> slots 4e+1..4e+4 ----
    for (int i = tid; i < WIN_ROWS * 32; i += 256) {
        int row = i >> 5, e = i & 31;
        int ic = row / WROWS, rr = row - ic * WROWS;
        int gr = gr0 + rr;
        float4 v = {0.f, 0.f, 0.f, 0.f};
        if ((unsigned)gr < (unsigned)HWDIM)
            v = *(const float4*)(ximg + ((size_t)(ic * HWDIM + gr) << 7) + 4 * e);
        int base = row * WIN_STRIDE + 1 + 4 * e;
        win[base + 0] = f2bf(v.x);
        win[base + 1] = f2bf(v.y);
        win[base + 2] = f2bf(v.z);
        win[base + 3] = f2bf(v.w);
    }
    __syncthreads();

    int l = tid & 63, wv = tid >> 6;
    int m15 = l & 15, kgrp = l >> 4;

    for (int ncol = 0; ncol < 2; ++ncol) {
        int nbase = (wv * 2 + ncol) * 64;          // this wave's 64-oc column
        int ntbase = nbase >> 4;
        float bias[4];
#pragma unroll
        for (int nt = 0; nt < 4; ++nt) bias[nt] = cb[nbase + nt * 16 + m15];
        float pool[4] = {0.f, 0.f, 0.f, 0.f};

        for (int mst = 0; mst < 2; ++mst) {        // 2 M-supertiles (2 rows each)
            f32x4 acc[4][4];
            const f32x4 z = {0.f, 0.f, 0.f, 0.f};
#pragma unroll
            for (int mt = 0; mt < 4; ++mt)
#pragma unroll
                for (int nt = 0; nt < 4; ++nt) acc[mt][nt] = z;

            bf16x8 bfA[4], bfB[4];
            load_bf(wtb, 0, ntbase, l, bfA);       // prologue: kt=0
#pragma unroll 1
            for (int kt2 = 0; kt2 < 3; ++kt2) {    // kt pairs: (0,1),(2,3),(4,5)
                load_bf(wtb, 2 * kt2 + 1, ntbase, l, bfB);   // prefetch odd kt
                compute_kt(win, 2 * kt2, kgrp, m15, mst, bfA, acc);
                if (kt2 < 2)
                    load_bf(wtb, 2 * kt2 + 2, ntbase, l, bfA); // prefetch next even
                compute_kt(win, 2 * kt2 + 1, kgrp, m15, mst, bfB, acc);
            }
            // bias + ReLU per conv output, accumulate pool partial per oc
#pragma unroll
            for (int mt = 0; mt < 4; ++mt)
#pragma unroll
                for (int nt = 0; nt < 4; ++nt)
#pragma unroll
                    for (int r = 0; r < 4; ++r)
                        pool[nt] += fmaxf(acc[mt][nt][r] + bias[nt], 0.f);
        }
        // reduce over the 4 k-chunk lane groups (disjoint positions)
#pragma unroll
        for (int nt = 0; nt < 4; ++nt) {
            float v = pool[nt];
            v += __shfl_xor(v, 16);
            v += __shfl_xor(v, 32);
            if (l < 16) partial[(size_t)wg * FV + nbase + nt * 16 + m15] = v;
        }
    }
}

// ---------------------------------------------------------------------------
// Kernel 2: per-sample head. float4 strip sums; per-wave projection.
// ---------------------------------------------------------------------------
__global__ __launch_bounds__(256) void head_kernel(
    const float* __restrict__ partial, const int* __restrict__ nslice,
    const float* __restrict__ q0, const float* __restrict__ pw,
    const float* __restrict__ pb, float* __restrict__ out)
{
    __shared__ float fvs[NS][FV];
    __shared__ float sc[NS];
    __shared__ float r0[FV];
    int b = blockIdx.x;
    int tid = threadIdx.x;

    for (int i = tid; i < NS * (FV / 4); i += 256) {
        int s = i >> 7, d4 = i & 127;
        const float* pp = partial + ((size_t)(b * NS + s) * STRIPS) * FV + 4 * d4;
        float4 a = {0.f, 0.f, 0.f, 0.f};
#pragma unroll
        for (int st = 0; st < STRIPS; ++st) {
            float4 v = *(const float4*)(pp + (size_t)st * FV);
            a.x += v.x; a.y += v.y; a.z += v.z; a.w += v.w;
        }
        const float sc4 = 1.f / 1024.f;
        float4 r = {a.x * sc4, a.y * sc4, a.z * sc4, a.w * sc4};
        *(float4*)&fvs[s][4 * d4] = r;
    }
    __syncthreads();

    int grp = tid >> 5, l32 = tid & 31;
    float sdot = 0.f;
    for (int d = l32; d < FV; d += 32) sdot += q0[d] * fvs[grp][d];
    sdot += __shfl_down(sdot, 16, 32);
    sdot += __shfl_down(sdot, 8, 32);
    sdot += __shfl_down(sdot, 4, 32);
    sdot += __shfl_down(sdot, 2, 32);
    sdot += __shfl_down(sdot, 1, 32);
    if (l32 == 0) sc[grp] = sdot;
    __syncthreads();

    int ns = nslice[b];
    float m = -3.0e38f;
    for (int s = 0; s < NS; ++s) if (s < ns) m = fmaxf(m, sc[s]);
    float ak[NS]; float se = 0.f;
    for (int s = 0; s < NS; ++s) {
        float e = (s < ns) ? expf(sc[s] - m) : 0.f;
        ak[s] = e; se += e;
    }
    float inv = 1.f / se;

    for (int d = tid; d < FV; d += 256) {
        float v = 0.f;
        for (int s = 0; s < NS; ++s) v += ak[s] * fvs[s][d];
        r0[d] = v * inv;
    }
    __syncthreads();

    int wv = tid >> 6, l = tid & 63;
    for (int k = wv; k < KOUT; k += 4) {
        float p = 0.f;
#pragma unroll
        for (int t = 0; t < 8; ++t) p += r0[l + 64 * t] * pw[k * FV + l + 64 * t];
        p += __shfl_down(p, 32);
        p += __shfl_down(p, 16);
        p += __shfl_down(p, 8);
        p += __shfl_down(p, 4);
        p += __shfl_down(p, 2);
        p += __shfl_down(p, 1);
        if (l == 0) out[b * KOUT + k] = 1.f / (1.f + expf(-(p + pb[k])));
    }
}

extern "C" void kernel_launch(void* const* d_in, const int* in_sizes, int n_in,
                              void* d_out, int out_size, void* d_ws, size_t ws_size,
                              hipStream_t stream) {
    (void)in_sizes; (void)n_in; (void)out_size; (void)ws_size;
    const float* x      = (const float*)d_in[0];
    const int*   nslice = (const int*)d_in[1];
    const float* cw     = (const float*)d_in[2];
    const float* cb     = (const float*)d_in[3];
    const float* q0     = (const float*)d_in[4];
    const float* pw     = (const float*)d_in[5];
    const float* pb     = (const float*)d_in[6];
    float* out = (float*)d_out;

    float* partial = (float*)d_ws;          // 1024*512 f32 = 2 MB
    unsigned short* wtb = (unsigned short*)(partial + (size_t)NIMG * STRIPS * FV);

    wprep_kernel<<<WTB_ELEMS / 256, 256, 0, stream>>>(cw, wtb);
    conv_mfma_kernel<<<NIMG * STRIPS, 256, 0, stream>>>(x, wtb, cb, partial);
    head_kernel<<<NB, 256, 0, stream>>>(partial, nslice, q0, pw, pb, out);
}

// Round 10
// 114.865 us; speedup vs baseline: 4.0008x; 1.1988x over previous
//
#include <hip/hip_runtime.h>

// Problem constants
#define NB 16
#define NS 8
#define NIMG (NB*NS)        // 128 images
#define CIN 3
#define HWDIM 128
#define FV 512
#define KOUT 10
#define STRIPS 8            // strip = 4 output rows (out 32x32, stride-4 7x7 SAME)
#define WROWS 19            // input rows per channel for 4 output rows
#define WIN_ROWS (CIN*WROWS)     // 57
#define WIN_STRIDE 136      // ushorts per row (272 B); slot = col + 1
#define NKT 6               // K-tiles of 32: 24 kb-blocks (21 real = ic*7+ky, 3 zero)
#define WTB_ELEMS (NKT*32*64*8)  // 98304 bf16 = 192 KB packed weight fragments

typedef __attribute__((ext_vector_type(8))) short bf16x8;   // 8 bf16 = 4 VGPR
typedef __attribute__((ext_vector_type(4))) float f32x4;    // MFMA acc

__device__ __forceinline__ unsigned short f2bf(float f) {   // RNE fp32->bf16
    unsigned int u = __float_as_uint(f);
    u = (u + 0x7FFFu + ((u >> 16) & 1u)) >> 16;
    return (unsigned short)u;
}

// ---------------------------------------------------------------------------
// Kernel 0a: zero the packed weight buffer (pads stay zero after fill).
// ---------------------------------------------------------------------------
__global__ void wzero_kernel(unsigned short* __restrict__ wtb) {
    int i = blockIdx.x * 256 + threadIdx.x;        // < 12288
    ((bf16x8*)wtb)[i] = (bf16x8){0,0,0,0,0,0,0,0};
}

// ---------------------------------------------------------------------------
// Kernel 0b: fill fragments, SRC-indexed (coalesced reads, scattered writes).
// wtb[kt][ntile(32)][lane(64)][8]: lane l holds B[k=kt*32+(l>>4)*8+j][oc=nt*16+(l&15)]
// with k=(kb=ic*7+ky, kx=j).
// ---------------------------------------------------------------------------
__global__ void wfill_kernel(const float* __restrict__ cw,
                             unsigned short* __restrict__ wtb) {
    int i = blockIdx.x * 256 + threadIdx.x;        // < 512*147
    if (i < FV * 147) {
        int oc = i / 147, tap = i - oc * 147;
        int kb = tap / 7, j = tap - kb * 7;        // j in 0..6 (j==7 pad untouched)
        int kt = kb >> 2, kg = kb & 3;
        size_t dst = (((size_t)(kt * 32 + (oc >> 4)) * 64 + kg * 16 + (oc & 15)) << 3) + j;
        wtb[dst] = f2bf(cw[i]);
    }
}

// ---------------------------------------------------------------------------
// Kernel 1: bf16-MFMA implicit-GEMM conv + bias + ReLU + pool partials.
// WG = (image, 4-row strip); grid 1024; launch_bounds(256,3).
// Register plan (slim): acc 64 + B single-buffer 16 + q/at ~16 + misc ~30
// ~= 125 << 170 cap -> no spill at 3 blocks/CU (12 waves).
// A-path: 3 ds_read_b64 per (kt,row-pair) — parity fragments share 4 shorts:
// at0={q0,q1}, at1={q1,q2}. B L2 latency hidden by TLP.
// ---------------------------------------------------------------------------
__global__ __launch_bounds__(256, 3) void conv_mfma_kernel(
    const float* __restrict__ x, const unsigned short* __restrict__ wtb,
    const float* __restrict__ cb, float* __restrict__ partial)
{
    __shared__ unsigned short win[WIN_ROWS * WIN_STRIDE];   // 15,504 B

    int wg = blockIdx.x, img = wg >> 3, strip = wg & 7, tid = threadIdx.x;
    const float* ximg = x + (size_t)img * (CIN * HWDIM * HWDIM);
    int gr0 = strip * 16 - 1;            // SAME pad: 1 top/left

    // ---- zero pad slots: slot 0 and slots 129..135 of each row ----
    for (int i = tid; i < WIN_ROWS * 8; i += 256) {
        int row = i >> 3, z = i & 7;
        int slot = z ? 128 + z : 0;
        win[row * WIN_STRIDE + slot] = 0;
    }
    // ---- main staging: row = ic*19+rr, cols 4e..4e+3 -> slots 4e+1..4e+4 ----
    for (int i = tid; i < WIN_ROWS * 32; i += 256) {
        int row = i >> 5, e = i & 31;
        int ic = row / WROWS, rr = row - ic * WROWS;
        int gr = gr0 + rr;
        float4 v = {0.f, 0.f, 0.f, 0.f};
        if ((unsigned)gr < (unsigned)HWDIM)
            v = *(const float4*)(ximg + ((size_t)(ic * HWDIM + gr) << 7) + 4 * e);
        int base = row * WIN_STRIDE + 1 + 4 * e;
        win[base + 0] = f2bf(v.x);
        win[base + 1] = f2bf(v.y);
        win[base + 2] = f2bf(v.z);
        win[base + 3] = f2bf(v.w);
    }
    __syncthreads();

    int l = tid & 63, wv = tid >> 6;
    int m15 = l & 15, kgrp = l >> 4;

#pragma unroll 1
    for (int ncol = 0; ncol < 2; ++ncol) {
        int nbase = (wv * 2 + ncol) * 64;          // this wave's 64-oc column
        int ntbase = nbase >> 4;
        float bias[4];
#pragma unroll
        for (int nt = 0; nt < 4; ++nt) bias[nt] = cb[nbase + nt * 16 + m15];
        float pool[4] = {0.f, 0.f, 0.f, 0.f};

#pragma unroll 1
        for (int mst = 0; mst < 2; ++mst) {        // 2 M-supertiles (2 rows each)
            f32x4 acc[4][4];
            const f32x4 z = {0.f, 0.f, 0.f, 0.f};
#pragma unroll
            for (int mt = 0; mt < 4; ++mt)
#pragma unroll
                for (int nt = 0; nt < 4; ++nt) acc[mt][nt] = z;

#pragma unroll 1
            for (int kt = 0; kt < NKT; ++kt) {
                // B fragments (single-buffered, L2-hot, 1KB/wave each)
                bf16x8 bfc[4];
#pragma unroll
                for (int nt = 0; nt < 4; ++nt)
                    bfc[nt] = *(const bf16x8*)(wtb +
                        (((size_t)(kt * 32 + ntbase + nt) * 64 + l) << 3));

                // window rows for this k-chunk: kb=(ic,ky); kb>=21 -> B zero
                int kb = kt * 4 + kgrp;
                int ic = (kb < 21) ? kb / 7 : 0;
                int ky = (kb < 21) ? kb - 7 * ic : 0;
                int rb = ic * WROWS + ky + mst * 8;

                // 3 b64 per row-pair; parity frags overlap 4 shorts
                unsigned long long q[2][3];
#pragma unroll
                for (int h = 0; h < 2; ++h) {
                    const unsigned short* p = win + (rb + h * 4) * WIN_STRIDE + 8 * m15;
                    q[h][0] = *(const unsigned long long*)(p);
                    q[h][1] = *(const unsigned long long*)(p + 4);
                    q[h][2] = *(const unsigned long long*)(p + 8);
                }
                union { unsigned long long qq[2]; bf16x8 v; } u0, u1, u2, u3;
                u0.qq[0] = q[0][0]; u0.qq[1] = q[0][1];   // row0 parity0
                u1.qq[0] = q[0][1]; u1.qq[1] = q[0][2];   // row0 parity1
                u2.qq[0] = q[1][0]; u2.qq[1] = q[1][1];   // row1 parity0
                u3.qq[0] = q[1][1]; u3.qq[1] = q[1][2];   // row1 parity1
                bf16x8 at[4] = {u0.v, u1.v, u2.v, u3.v};

#pragma unroll
                for (int mt = 0; mt < 4; ++mt)
#pragma unroll
                    for (int nt = 0; nt < 4; ++nt)
                        acc[mt][nt] = __builtin_amdgcn_mfma_f32_16x16x32_bf16(
                            at[mt], bfc[nt], acc[mt][nt], 0, 0, 0);
            }
            // bias + ReLU per conv output, accumulate pool partial per oc
#pragma unroll
            for (int mt = 0; mt < 4; ++mt)
#pragma unroll
                for (int nt = 0; nt < 4; ++nt)
#pragma unroll
                    for (int r = 0; r < 4; ++r)
                        pool[nt] += fmaxf(acc[mt][nt][r] + bias[nt], 0.f);
        }
        // reduce over the 4 k-chunk lane groups (disjoint positions)
#pragma unroll
        for (int nt = 0; nt < 4; ++nt) {
            float v = pool[nt];
            v += __shfl_xor(v, 16);
            v += __shfl_xor(v, 32);
            if (l < 16) partial[(size_t)wg * FV + nbase + nt * 16 + m15] = v;
        }
    }
}

// ---------------------------------------------------------------------------
// Kernel 2a: per-(image,slice) strip-sum + score. Grid 128.
// ---------------------------------------------------------------------------
__global__ __launch_bounds__(256) void head_fvs_kernel(
    const float* __restrict__ partial, const float* __restrict__ q0,
    float* __restrict__ fvs, float* __restrict__ sc)
{
    __shared__ float red[4];
    int img = blockIdx.x, tid = threadIdx.x;
    float dot = 0.f;
    for (int d = tid; d < FV; d += 256) {          // 2 iterations
        float v = 0.f;
#pragma unroll
        for (int st = 0; st < STRIPS; ++st)
            v += partial[((size_t)(img * STRIPS + st)) * FV + d];
        v *= (1.f / 1024.f);
        fvs[(size_t)img * FV + d] = v;
        dot += q0[d] * v;
    }
    dot += __shfl_down(dot, 32);
    dot += __shfl_down(dot, 16);
    dot += __shfl_down(dot, 8);
    dot += __shfl_down(dot, 4);
    dot += __shfl_down(dot, 2);
    dot += __shfl_down(dot, 1);
    int wv = tid >> 6, l = tid & 63;
    if (l == 0) red[wv] = dot;
    __syncthreads();
    if (tid == 0) sc[img] = red[0] + red[1] + red[2] + red[3];
}

// ---------------------------------------------------------------------------
// Kernel 2b: per-(sample,k) softmax-weighted projection + sigmoid. Grid 160.
// ---------------------------------------------------------------------------
__global__ __launch_bounds__(256) void head_out_kernel(
    const float* __restrict__ fvs, const float* __restrict__ sc,
    const int* __restrict__ nslice, const float* __restrict__ pw,
    const float* __restrict__ pb, float* __restrict__ out)
{
    __shared__ float red[4];
    int b = blockIdx.x / KOUT, k = blockIdx.x - b * KOUT;
    int tid = threadIdx.x;
    int ns = nslice[b];

    float m = -3.0e38f;
    for (int s = 0; s < NS; ++s) if (s < ns) m = fmaxf(m, sc[b * NS + s]);
    float ak[NS]; float se = 0.f;
    for (int s = 0; s < NS; ++s) {
        float e = (s < ns) ? expf(sc[b * NS + s] - m) : 0.f;
        ak[s] = e; se += e;
    }
    float inv = 1.f / se;

    float p = 0.f;
    for (int d = tid; d < FV; d += 256) {          // 2 iterations
        float r = 0.f;
#pragma unroll
        for (int s = 0; s < NS; ++s)
            r += ak[s] * fvs[(size_t)(b * NS + s) * FV + d];
        p += (r * inv) * pw[(size_t)k * FV + d];
    }
    p += __shfl_down(p, 32);
    p += __shfl_down(p, 16);
    p += __shfl_down(p, 8);
    p += __shfl_down(p, 4);
    p += __shfl_down(p, 2);
    p += __shfl_down(p, 1);
    int wv = tid >> 6, l = tid & 63;
    if (l == 0) red[wv] = p;
    __syncthreads();
    if (tid == 0) {
        float t = red[0] + red[1] + red[2] + red[3] + pb[k];
        out[b * KOUT + k] = 1.f / (1.f + expf(-t));
    }
}

extern "C" void kernel_launch(void* const* d_in, const int* in_sizes, int n_in,
                              void* d_out, int out_size, void* d_ws, size_t ws_size,
                              hipStream_t stream) {
    (void)in_sizes; (void)n_in; (void)out_size; (void)ws_size;
    const float* x      = (const float*)d_in[0];
    const int*   nslice = (const int*)d_in[1];
    const float* cw     = (const float*)d_in[2];
    const float* cb     = (const float*)d_in[3];
    const float* q0     = (const float*)d_in[4];
    const float* pw     = (const float*)d_in[5];
    const float* pb     = (const float*)d_in[6];
    float* out = (float*)d_out;

    float* partial = (float*)d_ws;                        // 1024*512 f32 = 2 MB
    unsigned short* wtb = (unsigned short*)(partial + (size_t)NIMG * STRIPS * FV);
    float* fvs = (float*)(wtb + WTB_ELEMS);               // 128*512 f32
    float* sc  = fvs + (size_t)NIMG * FV;                 // 128 f32

    wzero_kernel<<<WTB_ELEMS / 8 / 256, 256, 0, stream>>>(wtb);
    wfill_kernel<<<(FV * 147 + 255) / 256, 256, 0, stream>>>(cw, wtb);
    conv_mfma_kernel<<<NIMG * STRIPS, 256, 0, stream>>>(x, wtb, cb, partial);
    head_fvs_kernel<<<NIMG, 256, 0, stream>>>(partial, q0, fvs, sc);
    head_out_kernel<<<NB * KOUT, 256, 0, stream>>>(fvs, sc, nslice, pw, pb, out);
}

// Round 11
// 112.748 us; speedup vs baseline: 4.0759x; 1.0188x over previous
//
#include <hip/hip_runtime.h>

// Problem constants
#define NB 16
#define NS 8
#define NIMG (NB*NS)        // 128 images
#define CIN 3
#define HWDIM 128
#define FV 512
#define KOUT 10
#define STRIPS 8            // strip = 4 output rows (out 32x32, stride-4 7x7 SAME)
#define WROWS 19            // input rows per channel for 4 output rows
#define WIN_ROWS (CIN*WROWS)     // 57
#define WIN_STRIDE 136      // ushorts per row (272 B); slot = col + 1
#define NKT 6               // K-tiles of 32: 24 kb-blocks (21 real = ic*7+ky, 3 zero)
#define WTB_ELEMS (NKT*32*64*8)  // 98304 bf16 = 192 KB packed weight fragments

typedef __attribute__((ext_vector_type(8))) short bf16x8;   // 8 bf16 = 4 VGPR
typedef __attribute__((ext_vector_type(4))) float f32x4;    // MFMA acc

__device__ __forceinline__ unsigned short f2bf(float f) {   // RNE fp32->bf16
    unsigned int u = __float_as_uint(f);
    u = (u + 0x7FFFu + ((u >> 16) & 1u)) >> 16;
    return (unsigned short)u;
}

// ---------------------------------------------------------------------------
// Kernel 0: pack weights into MFMA B-fragment order (single pass, dst-indexed;
// pads written as zero). wtb[kt][ntile(32)][lane(64)][8]: lane l holds
// B[k=kt*32+(l>>4)*8+j][oc=nt*16+(l&15)], k=(kb=ic*7+ky, kx=j); zero for
// kb>=21 or j==7.
// ---------------------------------------------------------------------------
__global__ void wprep_kernel(const float* __restrict__ cw,
                             unsigned short* __restrict__ wtb) {
    int i = blockIdx.x * 256 + threadIdx.x;        // < 98304
    int j  = i & 7;
    int l  = (i >> 3) & 63;
    int nt = (i >> 9) & 31;
    int kt = i >> 14;
    int oc = nt * 16 + (l & 15);
    int kb = kt * 4 + (l >> 4);
    unsigned short v = 0;
    if (kb < 21 && j < 7) {
        int ic = kb / 7, ky = kb - 7 * ic;
        v = f2bf(cw[(size_t)oc * 147 + ic * 49 + ky * 7 + j]);
    }
    wtb[i] = v;
}

// ---------------------------------------------------------------------------
// Kernel 1: bf16-MFMA implicit-GEMM conv + bias + ReLU + pool partials.
// WG = (image, 4-row strip); grid 1024; launch_bounds(256,3); slim register
// plan (acc 64 + B 16 + staging v[] 32 transient + misc) -> no spill.
// Staging: phase-split load-all (8 float4 in flight -> 8x MLP) then
// convert+ds_write. A-path: 3 ds_read_b64 per (kt,row-pair) — parity
// fragments share 4 shorts. B single-buffered from L2-hot wtb; latency
// hidden by 12 waves/CU TLP.
// ---------------------------------------------------------------------------
__global__ __launch_bounds__(256, 3) void conv_mfma_kernel(
    const float* __restrict__ x, const unsigned short* __restrict__ wtb,
    const float* __restrict__ cb, float* __restrict__ partial)
{
    __shared__ unsigned short win[WIN_ROWS * WIN_STRIDE];   // 15,504 B

    int wg = blockIdx.x, img = wg >> 3, strip = wg & 7, tid = threadIdx.x;
    const float* ximg = x + (size_t)img * (CIN * HWDIM * HWDIM);
    int gr0 = strip * 16 - 1;            // SAME pad: 1 top/left

    // ---- zero pad slots: slot 0 and slots 129..135 of each row ----
    for (int i = tid; i < WIN_ROWS * 8; i += 256) {
        int row = i >> 3, z = i & 7;
        int slot = z ? 128 + z : 0;
        win[row * WIN_STRIDE + slot] = 0;
    }
    // ---- main staging, phase 1: issue all global loads (8 in flight) ----
    float4 v[8];
#pragma unroll
    for (int j = 0; j < 8; ++j) {
        int i = tid + j * 256;
        if (i < WIN_ROWS * 32) {
            int row = i >> 5, e = i & 31;
            int ic = row / WROWS, rr = row - ic * WROWS;
            int gr = gr0 + rr;
            float4 t = {0.f, 0.f, 0.f, 0.f};
            if ((unsigned)gr < (unsigned)HWDIM)
                t = *(const float4*)(ximg + ((size_t)(ic * HWDIM + gr) << 7) + 4 * e);
            v[j] = t;
        }
    }
    // ---- phase 2: convert + LDS write (row=ic*19+rr, slots 4e+1..4e+4) ----
#pragma unroll
    for (int j = 0; j < 8; ++j) {
        int i = tid + j * 256;
        if (i < WIN_ROWS * 32) {
            int row = i >> 5, e = i & 31;
            int base = row * WIN_STRIDE + 1 + 4 * e;
            win[base + 0] = f2bf(v[j].x);
            win[base + 1] = f2bf(v[j].y);
            win[base + 2] = f2bf(v[j].z);
            win[base + 3] = f2bf(v[j].w);
        }
    }
    __syncthreads();

    int l = tid & 63, wv = tid >> 6;
    int m15 = l & 15, kgrp = l >> 4;

#pragma unroll 1
    for (int ncol = 0; ncol < 2; ++ncol) {
        int nbase = (wv * 2 + ncol) * 64;          // this wave's 64-oc column
        int ntbase = nbase >> 4;
        float bias[4];
#pragma unroll
        for (int nt = 0; nt < 4; ++nt) bias[nt] = cb[nbase + nt * 16 + m15];
        float pool[4] = {0.f, 0.f, 0.f, 0.f};

#pragma unroll 1
        for (int mst = 0; mst < 2; ++mst) {        // 2 M-supertiles (2 rows each)
            f32x4 acc[4][4];
            const f32x4 z = {0.f, 0.f, 0.f, 0.f};
#pragma unroll
            for (int mt = 0; mt < 4; ++mt)
#pragma unroll
                for (int nt = 0; nt < 4; ++nt) acc[mt][nt] = z;

#pragma unroll 1
            for (int kt = 0; kt < NKT; ++kt) {
                // B fragments (single-buffered, L2-hot, 1KB/wave each)
                bf16x8 bfc[4];
#pragma unroll
                for (int nt = 0; nt < 4; ++nt)
                    bfc[nt] = *(const bf16x8*)(wtb +
                        (((size_t)(kt * 32 + ntbase + nt) * 64 + l) << 3));

                // window rows for this k-chunk: kb=(ic,ky); kb>=21 -> B zero
                int kb = kt * 4 + kgrp;
                int ic = (kb < 21) ? kb / 7 : 0;
                int ky = (kb < 21) ? kb - 7 * ic : 0;
                int rb = ic * WROWS + ky + mst * 8;

                // 3 b64 per row-pair; parity frags overlap 4 shorts
                unsigned long long q[2][3];
#pragma unroll
                for (int h = 0; h < 2; ++h) {
                    const unsigned short* p = win + (rb + h * 4) * WIN_STRIDE + 8 * m15;
                    q[h][0] = *(const unsigned long long*)(p);
                    q[h][1] = *(const unsigned long long*)(p + 4);
                    q[h][2] = *(const unsigned long long*)(p + 8);
                }
                union { unsigned long long qq[2]; bf16x8 v; } u0, u1, u2, u3;
                u0.qq[0] = q[0][0]; u0.qq[1] = q[0][1];   // row0 parity0
                u1.qq[0] = q[0][1]; u1.qq[1] = q[0][2];   // row0 parity1
                u2.qq[0] = q[1][0]; u2.qq[1] = q[1][1];   // row1 parity0
                u3.qq[0] = q[1][1]; u3.qq[1] = q[1][2];   // row1 parity1
                bf16x8 at[4] = {u0.v, u1.v, u2.v, u3.v};

#pragma unroll
                for (int mt = 0; mt < 4; ++mt)
#pragma unroll
                    for (int nt = 0; nt < 4; ++nt)
                        acc[mt][nt] = __builtin_amdgcn_mfma_f32_16x16x32_bf16(
                            at[mt], bfc[nt], acc[mt][nt], 0, 0, 0);
            }
            // bias + ReLU per conv output, accumulate pool partial per oc
#pragma unroll
            for (int mt = 0; mt < 4; ++mt)
#pragma unroll
                for (int nt = 0; nt < 4; ++nt)
#pragma unroll
                    for (int r = 0; r < 4; ++r)
                        pool[nt] += fmaxf(acc[mt][nt][r] + bias[nt], 0.f);
        }
        // reduce over the 4 k-chunk lane groups (disjoint positions)
#pragma unroll
        for (int nt = 0; nt < 4; ++nt) {
            float v2 = pool[nt];
            v2 += __shfl_xor(v2, 16);
            v2 += __shfl_xor(v2, 32);
            if (l < 16) partial[(size_t)wg * FV + nbase + nt * 16 + m15] = v2;
        }
    }
}

// ---------------------------------------------------------------------------
// Kernel 2a: per-image strip-sum + score. Grid 128.
// ---------------------------------------------------------------------------
__global__ __launch_bounds__(256) void head_fvs_kernel(
    const float* __restrict__ partial, const float* __restrict__ q0,
    float* __restrict__ fvs, float* __restrict__ sc)
{
    __shared__ float red[4];
    int img = blockIdx.x, tid = threadIdx.x;
    float dot = 0.f;
    for (int d = tid; d < FV; d += 256) {          // 2 iterations
        float v = 0.f;
#pragma unroll
        for (int st = 0; st < STRIPS; ++st)
            v += partial[((size_t)(img * STRIPS + st)) * FV + d];
        v *= (1.f / 1024.f);
        fvs[(size_t)img * FV + d] = v;
        dot += q0[d] * v;
    }
    dot += __shfl_down(dot, 32);
    dot += __shfl_down(dot, 16);
    dot += __shfl_down(dot, 8);
    dot += __shfl_down(dot, 4);
    dot += __shfl_down(dot, 2);
    dot += __shfl_down(dot, 1);
    int wv = tid >> 6, l = tid & 63;
    if (l == 0) red[wv] = dot;
    __syncthreads();
    if (tid == 0) sc[img] = red[0] + red[1] + red[2] + red[3];
}

// ---------------------------------------------------------------------------
// Kernel 2b: per-(sample,k) softmax-weighted projection + sigmoid. Grid 160.
// ---------------------------------------------------------------------------
__global__ __launch_bounds__(256) void head_out_kernel(
    const float* __restrict__ fvs, const float* __restrict__ sc,
    const int* __restrict__ nslice, const float* __restrict__ pw,
    const float* __restrict__ pb, float* __restrict__ out)
{
    __shared__ float red[4];
    int b = blockIdx.x / KOUT, k = blockIdx.x - b * KOUT;
    int tid = threadIdx.x;
    int ns = nslice[b];

    float m = -3.0e38f;
    for (int s = 0; s < NS; ++s) if (s < ns) m = fmaxf(m, sc[b * NS + s]);
    float ak[NS]; float se = 0.f;
    for (int s = 0; s < NS; ++s) {
        float e = (s < ns) ? expf(sc[b * NS + s] - m) : 0.f;
        ak[s] = e; se += e;
    }
    float inv = 1.f / se;

    float p = 0.f;
    for (int d = tid; d < FV; d += 256) {          // 2 iterations
        float r = 0.f;
#pragma unroll
        for (int s = 0; s < NS; ++s)
            r += ak[s] * fvs[(size_t)(b * NS + s) * FV + d];
        p += (r * inv) * pw[(size_t)k * FV + d];
    }
    p += __shfl_down(p, 32);
    p += __shfl_down(p, 16);
    p += __shfl_down(p, 8);
    p += __shfl_down(p, 4);
    p += __shfl_down(p, 2);
    p += __shfl_down(p, 1);
    int wv = tid >> 6, l = tid & 63;
    if (l == 0) red[wv] = p;
    __syncthreads();
    if (tid == 0) {
        float t = red[0] + red[1] + red[2] + red[3] + pb[k];
        out[b * KOUT + k] = 1.f / (1.f + expf(-t));
    }
}

extern "C" void kernel_launch(void* const* d_in, const int* in_sizes, int n_in,
                              void* d_out, int out_size, void* d_ws, size_t ws_size,
                              hipStream_t stream) {
    (void)in_sizes; (void)n_in; (void)out_size; (void)ws_size;
    const float* x      = (const float*)d_in[0];
    const int*   nslice = (const int*)d_in[1];
    const float* cw     = (const float*)d_in[2];
    const float* cb     = (const float*)d_in[3];
    const float* q0     = (const float*)d_in[4];
    const float* pw     = (const float*)d_in[5];
    const float* pb     = (const float*)d_in[6];
    float* out = (float*)d_out;

    float* partial = (float*)d_ws;                        // 1024*512 f32 = 2 MB
    unsigned short* wtb = (unsigned short*)(partial + (size_t)NIMG * STRIPS * FV);
    float* fvs = (float*)(wtb + WTB_ELEMS);               // 128*512 f32
    float* sc  = fvs + (size_t)NIMG * FV;                 // 128 f32

    wprep_kernel<<<WTB_ELEMS / 256, 256, 0, stream>>>(cw, wtb);
    conv_mfma_kernel<<<NIMG * STRIPS, 256, 0, stream>>>(x, wtb, cb, partial);
    head_fvs_kernel<<<NIMG, 256, 0, stream>>>(partial, q0, fvs, sc);
    head_out_kernel<<<NB * KOUT, 256, 0, stream>>>(fvs, sc, nslice, pw, pb, out);
}